// Round 4
// baseline (254.722 us; speedup 1.0000x reference)
//
#include <hip/hip_runtime.h>

// Problem constants
#define NTOK   2048
#define DIM    64
#define NCODES 50000
#define THRESH 100.0f
#define BIG    3.0e38f
#define MARGIN 6.0f      // >= 2*E, E = bf16 dot error bound (~1.1); ~2.5x safety
#define NBLK   392       // 128-code blocks (196 tiles * 2)
#define CTILES 196
#define RS_WGS 1024
#define RS_WAVES (RS_WGS * 4)

typedef __attribute__((ext_vector_type(8)))  __bf16 bf16x8;
typedef __attribute__((ext_vector_type(16))) float  float16;

__device__ __forceinline__ unsigned short f2bf(float f) {
    union { float f; unsigned int u; } v; v.f = f;
    unsigned int r = v.u + 0x7FFF + ((v.u >> 16) & 1);
    return (unsigned short)(r >> 16);
}
__device__ __forceinline__ unsigned int pack2(float a, float b) {
    return (unsigned int)f2bf(a) | ((unsigned int)f2bf(b) << 16);
}

// ---------------------------------------------------------------------------
// Kernel 1 (prep): fp32 -> bf16 conversion of codes and x, plus norms.
// 4 lanes per row (each lane 64 contiguous bytes) -> coalesced loads/stores;
// 2-step shfl reduce for the norm. Thread 0 zeroes the pair counter.
// ---------------------------------------------------------------------------
__global__ __launch_bounds__(256)
void nn_prep_kernel(const float* __restrict__ x, const float* __restrict__ codes,
                    unsigned short* __restrict__ cbf, unsigned short* __restrict__ xbf,
                    float* __restrict__ c2, float* __restrict__ x2,
                    unsigned int* __restrict__ cnt) {
    int g = blockIdx.x * 256 + threadIdx.x;
    if (g == 0) *cnt = 0;
    int row = g >> 2;
    int seg = g & 3;
    const float* src;
    unsigned short* dst;
    float* nrm;
    if (row < NCODES) {
        src = codes + (size_t)row * DIM + seg * 16;
        dst = cbf + (size_t)row * DIM + seg * 16;
        nrm = (seg == 0) ? (c2 + row) : nullptr;
    } else if (row < NCODES + NTOK) {
        int r = row - NCODES;
        src = x + (size_t)r * DIM + seg * 16;
        dst = xbf + (size_t)r * DIM + seg * 16;
        nrm = (seg == 0) ? (x2 + r) : nullptr;
    } else {
        return;
    }
    float4 v0 = ((const float4*)src)[0];
    float4 v1 = ((const float4*)src)[1];
    float4 v2 = ((const float4*)src)[2];
    float4 v3 = ((const float4*)src)[3];
    float s = 0.f;
    s = fmaf(v0.x, v0.x, s); s = fmaf(v0.y, v0.y, s);
    s = fmaf(v0.z, v0.z, s); s = fmaf(v0.w, v0.w, s);
    s = fmaf(v1.x, v1.x, s); s = fmaf(v1.y, v1.y, s);
    s = fmaf(v1.z, v1.z, s); s = fmaf(v1.w, v1.w, s);
    s = fmaf(v2.x, v2.x, s); s = fmaf(v2.y, v2.y, s);
    s = fmaf(v2.z, v2.z, s); s = fmaf(v2.w, v2.w, s);
    s = fmaf(v3.x, v3.x, s); s = fmaf(v3.y, v3.y, s);
    s = fmaf(v3.z, v3.z, s); s = fmaf(v3.w, v3.w, s);
    uint4 lo, hi;
    lo.x = pack2(v0.x, v0.y); lo.y = pack2(v0.z, v0.w);
    lo.z = pack2(v1.x, v1.y); lo.w = pack2(v1.z, v1.w);
    hi.x = pack2(v2.x, v2.y); hi.y = pack2(v2.z, v2.w);
    hi.z = pack2(v3.x, v3.y); hi.w = pack2(v3.z, v3.w);
    *(uint4*)dst = lo;
    *(uint4*)(dst + 8) = hi;
    s += __shfl_xor(s, 1);
    s += __shfl_xor(s, 2);
    if (nrm) *nrm = s;
}

// ---------------------------------------------------------------------------
// Kernel 2 (stage A): bf16 MFMA screening, reading pre-converted bf16.
// Grid: (16 token-tiles of 128) x (196 code-tiles of 256). WG = 4 waves.
// MFMA 32x32x16_bf16, acc init -c2/2 so blockmin = -2*max(D).
// LDS rows padded to 72 bf16 (144 B): b128 accesses land 4/bank = minimum.
// ---------------------------------------------------------------------------
__global__ __launch_bounds__(256, 2)
void nn_stageA_kernel(const unsigned short* __restrict__ xbf,
                      const unsigned short* __restrict__ cbf,
                      const float* __restrict__ c2g,
                      float* __restrict__ blockmin) {
    __shared__ __bf16 cs[256 * 72];
    __shared__ __bf16 xs[128 * 72];
    __shared__ float  c2s[256];

    const int tid  = threadIdx.x;
    const int w    = tid >> 6;
    const int lane = tid & 63;
    const int l31  = lane & 31;
    const int h    = lane >> 5;
    const int wc   = w & 1;
    const int wt   = w >> 1;
    const int t0   = blockIdx.x * 128;
    const int n0   = blockIdx.y * 256;

    // codes tile: 256 rows x 128 B, 8 lanes/row, 16 B/lane — coalesced
#pragma unroll
    for (int it = 0; it < 8; ++it) {
        int g = it * 256 + tid;
        int row = g >> 3, seg = g & 7;
        int n = n0 + row;
        uint4 v = make_uint4(0, 0, 0, 0);
        if (n < NCODES) v = *(const uint4*)(cbf + (size_t)n * DIM + seg * 8);
        *(uint4*)&cs[row * 72 + seg * 8] = v;
    }
    // x tile: 128 rows x 128 B
#pragma unroll
    for (int it = 0; it < 4; ++it) {
        int g = it * 256 + tid;
        int row = g >> 3, seg = g & 7;
        uint4 v = *(const uint4*)(xbf + (size_t)(t0 + row) * DIM + seg * 8);
        *(uint4*)&xs[row * 72 + seg * 8] = v;
    }
    {
        int n = n0 + tid;
        c2s[tid] = (n < NCODES) ? c2g[n] : BIG;
    }
    __syncthreads();

    // acc[mi][nj][r] = -c2[code_row]/2
    // C/D: col = lane&31 (token), row = (r&3) + 8*(r>>2) + 4*h (code)
    float16 acc[4][2];
#pragma unroll
    for (int mi = 0; mi < 4; ++mi) {
#pragma unroll
        for (int g2 = 0; g2 < 4; ++g2) {
            float4 c4 = *(float4*)&c2s[wc * 128 + mi * 32 + g2 * 8 + 4 * h];
#pragma unroll
            for (int i = 0; i < 4; ++i) {
                float iv = -0.5f * ((float*)&c4)[i];
                acc[mi][0][g2 * 4 + i] = iv;
                acc[mi][1][g2 * 4 + i] = iv;
            }
        }
    }

    // MFMA main: K = 64 in 4 steps of 16
#pragma unroll
    for (int s = 0; s < 4; ++s) {
        bf16x8 a[4], b[2];
#pragma unroll
        for (int mi = 0; mi < 4; ++mi)
            a[mi] = *(bf16x8*)&cs[(wc * 128 + mi * 32 + l31) * 72 + s * 16 + h * 8];
#pragma unroll
        for (int nj = 0; nj < 2; ++nj)
            b[nj] = *(bf16x8*)&xs[(wt * 64 + nj * 32 + l31) * 72 + s * 16 + h * 8];
#pragma unroll
        for (int mi = 0; mi < 4; ++mi)
#pragma unroll
            for (int nj = 0; nj < 2; ++nj)
                acc[mi][nj] = __builtin_amdgcn_mfma_f32_32x32x16_bf16(
                    a[mi], b[nj], acc[mi][nj], 0, 0, 0);
    }

    // epilogue: per-token max(D) over this wave's 128 codes
#pragma unroll
    for (int nj = 0; nj < 2; ++nj) {
        float m = acc[0][nj][0];
#pragma unroll
        for (int mi = 0; mi < 4; ++mi)
#pragma unroll
            for (int r = 0; r < 16; ++r)
                m = fmaxf(m, acc[mi][nj][r]);
        m = fmaxf(m, __shfl_xor(m, 32));
        if (lane < 32) {
            int token = t0 + wt * 64 + nj * 32 + lane;
            blockmin[(size_t)token * NBLK + blockIdx.y * 2 + wc] = -2.0f * m;
        }
    }
}

// ---------------------------------------------------------------------------
// Kernel 3 (compact): per token — gmin over 392 blockmins, init packed slot,
// push candidate (token,block) pairs via wave-aggregated atomicAdd.
// ---------------------------------------------------------------------------
__global__ __launch_bounds__(256)
void nn_compact_kernel(const float* __restrict__ blockmin,
                       unsigned long long* __restrict__ packed,
                       unsigned int* __restrict__ cnt,
                       unsigned int* __restrict__ pairs) {
    const int w = threadIdx.x >> 6;
    const int lane = threadIdx.x & 63;
    const int t = blockIdx.x * 4 + w;
    const float* bm = blockmin + (size_t)t * NBLK;

    float v[7];
    float g = BIG;
#pragma unroll
    for (int i = 0; i < 7; ++i) {
        int b = i * 64 + lane;
        v[i] = (b < NBLK) ? bm[b] : BIG;
        g = fminf(g, v[i]);
    }
#pragma unroll
    for (int m = 1; m < 64; m <<= 1) g = fminf(g, __shfl_xor(g, m));
    const float th = g + MARGIN;

    if (lane == 0) packed[t] = ~0ULL;

#pragma unroll
    for (int i = 0; i < 7; ++i) {
        bool cand = (v[i] <= th);
        unsigned long long m = __ballot(cand);
        if (m) {
            int leader = __ffsll((long long)m) - 1;
            unsigned int base = 0;
            if (lane == leader) base = atomicAdd(cnt, (unsigned int)__popcll(m));
            base = (unsigned int)__shfl((int)base, leader);
            if (cand) {
                int off = __popcll(m & ((1ULL << lane) - 1ULL));
                pairs[base + off] = ((unsigned int)t << 9) | (unsigned int)(i * 64 + lane);
            }
        }
    }
}

// ---------------------------------------------------------------------------
// Kernel 4 (rescore): grid-stride over candidate pairs, one wave per pair.
// Exact fp32 rescore of 128 codes; combine via 64-bit atomicMin on
// (d2_bits<<32)|id — preserves first-occurrence tie-break (smaller id wins).
// ---------------------------------------------------------------------------
__global__ __launch_bounds__(256)
void nn_rescore_kernel(const float* __restrict__ x,
                       const float* __restrict__ codes,
                       const float* __restrict__ c2,
                       const float* __restrict__ x2,
                       const unsigned int* __restrict__ cnt,
                       const unsigned int* __restrict__ pairs,
                       unsigned long long* __restrict__ packed) {
    const int lane = threadIdx.x & 63;
    const int wid = blockIdx.x * 4 + (threadIdx.x >> 6);
    const int np = (int)*cnt;

    for (int p = wid; p < np; p += RS_WAVES) {
        unsigned int pr = pairs[p];
        int t = (int)(pr >> 9);
        int b = (int)(pr & 511u);

        float4 xr[16];
#pragma unroll
        for (int q = 0; q < 16; ++q)
            xr[q] = *(const float4*)(x + (size_t)t * DIM + q * 4);
        const float x2v = x2[t];

        float bv = BIG;
        int   bi = 0x7fffffff;
#pragma unroll
        for (int rep = 0; rep < 2; ++rep) {
            int n = b * 128 + rep * 64 + lane;
            if (n < NCODES) {
                const float4* cp = (const float4*)(codes + (size_t)n * DIM);
                float dot = 0.f;
#pragma unroll
                for (int q = 0; q < 16; ++q) {
                    float4 c4 = cp[q];
                    dot = fmaf(xr[q].x, c4.x, dot);
                    dot = fmaf(xr[q].y, c4.y, dot);
                    dot = fmaf(xr[q].z, c4.z, dot);
                    dot = fmaf(xr[q].w, c4.w, dot);
                }
                float d2 = fmaxf(fmaf(-2.f, dot, x2v + c2[n]), 0.f);
                if (d2 < bv || (d2 == bv && n < bi)) { bv = d2; bi = n; }
            }
        }
#pragma unroll
        for (int m = 1; m < 64; m <<= 1) {
            float vv = __shfl_xor(bv, m);
            int   ii = __shfl_xor(bi, m);
            if (vv < bv || (vv == bv && ii < bi)) { bv = vv; bi = ii; }
        }
        if (lane == 0) {
            unsigned long long key =
                ((unsigned long long)__float_as_uint(bv) << 32) | (unsigned int)bi;
            atomicMin(packed + t, key);
        }
    }
}

// ---------------------------------------------------------------------------
// Kernel 5 (emit): unpack, threshold, write int ids.
// ---------------------------------------------------------------------------
__global__ void nn_emit_kernel(const unsigned long long* __restrict__ packed,
                               int* __restrict__ out) {
    int t = blockIdx.x * 256 + threadIdx.x;
    if (t >= NTOK) return;
    unsigned long long k = packed[t];
    float d2 = __uint_as_float((unsigned int)(k >> 32));
    int id = (int)(k & 0xFFFFFFFFu);
    out[t] = (d2 <= THRESH) ? id : -1;
}

// ---------------------------------------------------------------------------
// Workspace layout (bytes):
//   c2[50048]f | x2[2048]f | cbf[50000*64]u16 | xbf[2048*64]u16 |
//   blockmin[2048*392]f | packed[2048]u64 | pairs[2048*392]u32 | cnt  (~13.3MB)
// ---------------------------------------------------------------------------
extern "C" void kernel_launch(void* const* d_in, const int* in_sizes, int n_in,
                              void* d_out, int out_size, void* d_ws, size_t ws_size,
                              hipStream_t stream) {
    const float* x     = (const float*)d_in[0];  // [2,1024,64]
    const float* codes = (const float*)d_in[1];  // [50000,64]

    float* c2 = (float*)d_ws;
    float* x2 = c2 + 50048;
    unsigned short* cbf = (unsigned short*)(x2 + NTOK);
    unsigned short* xbf = cbf + (size_t)NCODES * DIM;
    float* blockmin = (float*)(xbf + (size_t)NTOK * DIM);
    unsigned long long* packed = (unsigned long long*)(blockmin + (size_t)NTOK * NBLK);
    unsigned int* pairs = (unsigned int*)(packed + NTOK);
    unsigned int* cnt = pairs + (size_t)NTOK * NBLK;
    int* out = (int*)d_out;

    nn_prep_kernel<<<814, 256, 0, stream>>>(x, codes, cbf, xbf, c2, x2, cnt);
    nn_stageA_kernel<<<dim3(16, CTILES), 256, 0, stream>>>(xbf, cbf, c2, blockmin);
    nn_compact_kernel<<<NTOK / 4, 256, 0, stream>>>(blockmin, packed, cnt, pairs);
    nn_rescore_kernel<<<RS_WGS, 256, 0, stream>>>(x, codes, c2, x2, cnt, pairs, packed);
    nn_emit_kernel<<<(NTOK + 255) / 256, 256, 0, stream>>>(packed, out);
}

// Round 5
// 192.524 us; speedup vs baseline: 1.3231x; 1.3231x over previous
//
#include <hip/hip_runtime.h>

// Problem constants
#define NTOK   2048
#define DIM    64
#define NCODES 50000
#define THRESH 100.0f
#define BIG    3.0e38f
#define MARGIN 6.0f      // >= 2*E; measured bf16 dot err bound ~0.3, 10x safety
#define NBLK   391       // ceil(50000/128) code blocks of 128
#define GRP    56        // rescan: 7 groups of 56 cover 392 >= NBLK
#define NGRP   7

typedef __attribute__((ext_vector_type(8)))  __bf16 bf16x8;
typedef __attribute__((ext_vector_type(16))) float  float16;

__device__ __forceinline__ unsigned short f2bf(float f) {
    union { float f; unsigned int u; } v; v.f = f;
    unsigned int r = v.u + 0x7FFF + ((v.u >> 16) & 1);
    return (unsigned short)(r >> 16);
}
__device__ __forceinline__ unsigned int pack2(float a, float b) {
    return (unsigned int)f2bf(a) | ((unsigned int)f2bf(b) << 16);
}

// ---------------------------------------------------------------------------
// Kernel 1 (prep): fp32 -> bf16 of codes and x, norms, packed-slot init.
// 4 lanes per row (64 B per lane), 2-step shfl for the norm.
// ---------------------------------------------------------------------------
__global__ __launch_bounds__(256)
void nn_prep_kernel(const float* __restrict__ x, const float* __restrict__ codes,
                    unsigned short* __restrict__ cbf, unsigned short* __restrict__ xbf,
                    float* __restrict__ c2, float* __restrict__ x2,
                    unsigned long long* __restrict__ packed) {
    int g = blockIdx.x * 256 + threadIdx.x;
    if (g < NTOK) packed[g] = ~0ULL;
    int row = g >> 2;
    int seg = g & 3;
    const float* src;
    unsigned short* dst;
    float* nrm;
    if (row < NCODES) {
        src = codes + (size_t)row * DIM + seg * 16;
        dst = cbf + (size_t)row * DIM + seg * 16;
        nrm = (seg == 0) ? (c2 + row) : nullptr;
    } else if (row < NCODES + NTOK) {
        int r = row - NCODES;
        src = x + (size_t)r * DIM + seg * 16;
        dst = xbf + (size_t)r * DIM + seg * 16;
        nrm = (seg == 0) ? (x2 + r) : nullptr;
    } else {
        return;
    }
    float4 v0 = ((const float4*)src)[0];
    float4 v1 = ((const float4*)src)[1];
    float4 v2 = ((const float4*)src)[2];
    float4 v3 = ((const float4*)src)[3];
    float s = 0.f;
    s = fmaf(v0.x, v0.x, s); s = fmaf(v0.y, v0.y, s);
    s = fmaf(v0.z, v0.z, s); s = fmaf(v0.w, v0.w, s);
    s = fmaf(v1.x, v1.x, s); s = fmaf(v1.y, v1.y, s);
    s = fmaf(v1.z, v1.z, s); s = fmaf(v1.w, v1.w, s);
    s = fmaf(v2.x, v2.x, s); s = fmaf(v2.y, v2.y, s);
    s = fmaf(v2.z, v2.z, s); s = fmaf(v2.w, v2.w, s);
    s = fmaf(v3.x, v3.x, s); s = fmaf(v3.y, v3.y, s);
    s = fmaf(v3.z, v3.z, s); s = fmaf(v3.w, v3.w, s);
    uint4 lo, hi;
    lo.x = pack2(v0.x, v0.y); lo.y = pack2(v0.z, v0.w);
    lo.z = pack2(v1.x, v1.y); lo.w = pack2(v1.z, v1.w);
    hi.x = pack2(v2.x, v2.y); hi.y = pack2(v2.z, v2.w);
    hi.z = pack2(v3.x, v3.y); hi.w = pack2(v3.z, v3.w);
    *(uint4*)dst = lo;
    *(uint4*)(dst + 8) = hi;
    s += __shfl_xor(s, 1);
    s += __shfl_xor(s, 2);
    if (nrm) *nrm = s;
}

// ---------------------------------------------------------------------------
// Kernel 2 (stage A): bf16 MFMA screening.
// Grid: (8 token-supertiles of 256) x (391 code blocks of 128). WG = 4 waves.
// Wave w handles tokens w*64..w*64+63 x all 128 codes (4 m-tiles x 2 n-tiles).
// acc init -c2/2 so per-token blockmin = -2*max(D). Codes read 8x (51 MB,
// LLC); x read 391x but xbf = 256 KB -> L2-resident.
// ---------------------------------------------------------------------------
__global__ __launch_bounds__(256, 2)
void nn_stageA_kernel(const unsigned short* __restrict__ xbf,
                      const unsigned short* __restrict__ cbf,
                      const float* __restrict__ c2g,
                      float* __restrict__ blockmin) {
    __shared__ __bf16 xs[256 * 72];   // token tile, 144 B row stride
    __shared__ __bf16 cs[128 * 72];   // code tile
    __shared__ float  c2s[128];

    const int tid  = threadIdx.x;
    const int w    = tid >> 6;
    const int lane = tid & 63;
    const int l31  = lane & 31;
    const int h    = lane >> 5;
    const int t0   = blockIdx.x * 256;
    const int n0   = blockIdx.y * 128;

    // codes tile: 128 rows x 128 B, 8 lanes/row, 16 B/lane — coalesced
#pragma unroll
    for (int it = 0; it < 4; ++it) {
        int g = it * 256 + tid;
        int row = g >> 3, seg = g & 7;
        int n = n0 + row;
        uint4 v = make_uint4(0, 0, 0, 0);
        if (n < NCODES) v = *(const uint4*)(cbf + (size_t)n * DIM + seg * 8);
        *(uint4*)&cs[row * 72 + seg * 8] = v;
    }
    // x tile: 256 rows x 128 B
#pragma unroll
    for (int it = 0; it < 8; ++it) {
        int g = it * 256 + tid;
        int row = g >> 3, seg = g & 7;
        uint4 v = *(const uint4*)(xbf + (size_t)(t0 + row) * DIM + seg * 8);
        *(uint4*)&xs[row * 72 + seg * 8] = v;
    }
    if (tid < 128) {
        int n = n0 + tid;
        c2s[tid] = (n < NCODES) ? c2g[n] : BIG;
    }
    __syncthreads();

    // acc[mi][nj][r] = -c2[code_row]/2
    // C/D: col = lane&31 (token), row = (r&3) + 8*(r>>2) + 4*h (code)
    float16 acc[4][2];
#pragma unroll
    for (int mi = 0; mi < 4; ++mi) {
#pragma unroll
        for (int g2 = 0; g2 < 4; ++g2) {
            float4 c4 = *(float4*)&c2s[mi * 32 + g2 * 8 + 4 * h];
#pragma unroll
            for (int i = 0; i < 4; ++i) {
                float iv = -0.5f * ((float*)&c4)[i];
                acc[mi][0][g2 * 4 + i] = iv;
                acc[mi][1][g2 * 4 + i] = iv;
            }
        }
    }

    // MFMA main: K = 64 in 4 steps of 16
#pragma unroll
    for (int s = 0; s < 4; ++s) {
        bf16x8 a[4], b[2];
#pragma unroll
        for (int mi = 0; mi < 4; ++mi)
            a[mi] = *(bf16x8*)&cs[(mi * 32 + l31) * 72 + s * 16 + h * 8];
#pragma unroll
        for (int nj = 0; nj < 2; ++nj)
            b[nj] = *(bf16x8*)&xs[(w * 64 + nj * 32 + l31) * 72 + s * 16 + h * 8];
#pragma unroll
        for (int mi = 0; mi < 4; ++mi)
#pragma unroll
            for (int nj = 0; nj < 2; ++nj)
                acc[mi][nj] = __builtin_amdgcn_mfma_f32_32x32x16_bf16(
                    a[mi], b[nj], acc[mi][nj], 0, 0, 0);
    }

    // epilogue: per-token max(D) over all 128 codes of this block
#pragma unroll
    for (int nj = 0; nj < 2; ++nj) {
        float m = acc[0][nj][0];
#pragma unroll
        for (int mi = 0; mi < 4; ++mi)
#pragma unroll
            for (int r = 0; r < 16; ++r)
                m = fmaxf(m, acc[mi][nj][r]);
        m = fmaxf(m, __shfl_xor(m, 32));   // merge h halves (code rows +4)
        if (lane < 32) {
            int token = t0 + w * 64 + nj * 32 + lane;
            blockmin[(size_t)token * NBLK + blockIdx.y] = -2.0f * m;
        }
    }
}

// ---------------------------------------------------------------------------
// Kernel 3 (rescan): one wave per (token, group of 56 blocks).
// Wave reads all 391 blockmins for its token (L2-hit), computes
// gthresh = gmin + MARGIN locally (no producer kernel, no shared counter),
// ballots its own 56 blocks, rescores candidates exactly in fp32, and
// combines via atomicMin on packed[t] = (d2_bits<<32)|id (first-occurrence
// ties preserved: smaller id wins on equal d2).
// ---------------------------------------------------------------------------
__global__ __launch_bounds__(256)
void nn_rescan_kernel(const float* __restrict__ x,
                      const float* __restrict__ codes,
                      const float* __restrict__ c2,
                      const float* __restrict__ x2,
                      const float* __restrict__ blockmin,
                      unsigned long long* __restrict__ packed) {
    const int lane = threadIdx.x & 63;
    const unsigned int wid = blockIdx.x * 4 + (threadIdx.x >> 6);
    const int t = (int)(wid / NGRP);
    const int grp = (int)(wid - (unsigned int)t * NGRP);
    const float* bm = blockmin + (size_t)t * NBLK;

    // global min over all 391 blocks
    float g = BIG;
#pragma unroll
    for (int i = 0; i < 7; ++i) {
        int b = i * 64 + lane;
        if (b < NBLK) g = fminf(g, bm[b]);
    }
#pragma unroll
    for (int m = 1; m < 64; m <<= 1) g = fminf(g, __shfl_xor(g, m));
    const float th = g + MARGIN;

    // my group's candidacy
    int myb = grp * GRP + lane;
    bool cand = (lane < GRP) && (myb < NBLK) && (bm[myb] <= th);
    unsigned long long mask = __ballot(cand);
    if (mask == 0ULL) return;

    // load x[t] (wave-uniform broadcast)
    float4 xr[16];
#pragma unroll
    for (int q = 0; q < 16; ++q)
        xr[q] = *(const float4*)(x + (size_t)t * DIM + q * 4);
    const float x2v = x2[t];

    float bv = BIG;
    int   bi = 0x7fffffff;
    while (mask) {
        int sl = __ffsll((long long)mask) - 1;
        mask &= mask - 1;
        int blk = grp * GRP + sl;
#pragma unroll
        for (int rep = 0; rep < 2; ++rep) {
            int n = blk * 128 + rep * 64 + lane;
            if (n < NCODES) {
                const float4* cp = (const float4*)(codes + (size_t)n * DIM);
                float dot = 0.f;
#pragma unroll
                for (int q = 0; q < 16; ++q) {
                    float4 c4 = cp[q];
                    dot = fmaf(xr[q].x, c4.x, dot);
                    dot = fmaf(xr[q].y, c4.y, dot);
                    dot = fmaf(xr[q].z, c4.z, dot);
                    dot = fmaf(xr[q].w, c4.w, dot);
                }
                float d2 = fmaxf(fmaf(-2.f, dot, x2v + c2[n]), 0.f);
                if (d2 < bv || (d2 == bv && n < bi)) { bv = d2; bi = n; }
            }
        }
    }
#pragma unroll
    for (int m = 1; m < 64; m <<= 1) {
        float vv = __shfl_xor(bv, m);
        int   ii = __shfl_xor(bi, m);
        if (vv < bv || (vv == bv && ii < bi)) { bv = vv; bi = ii; }
    }
    if (lane == 0) {
        unsigned long long key =
            ((unsigned long long)__float_as_uint(bv) << 32) | (unsigned int)bi;
        atomicMin(packed + t, key);
    }
}

// ---------------------------------------------------------------------------
// Kernel 4 (emit): unpack, threshold, write int ids.
// ---------------------------------------------------------------------------
__global__ void nn_emit_kernel(const unsigned long long* __restrict__ packed,
                               int* __restrict__ out) {
    int t = blockIdx.x * 256 + threadIdx.x;
    if (t >= NTOK) return;
    unsigned long long k = packed[t];
    float d2 = __uint_as_float((unsigned int)(k >> 32));
    int id = (int)(k & 0xFFFFFFFFu);
    out[t] = (d2 <= THRESH) ? id : -1;
}

// ---------------------------------------------------------------------------
// Workspace: c2[50048]f | x2[2048]f | cbf[50000*64]u16 | xbf[2048*64]u16 |
//            blockmin[2048*391]f | packed[2048]u64   (~10.4 MB)
// ---------------------------------------------------------------------------
extern "C" void kernel_launch(void* const* d_in, const int* in_sizes, int n_in,
                              void* d_out, int out_size, void* d_ws, size_t ws_size,
                              hipStream_t stream) {
    const float* x     = (const float*)d_in[0];  // [2,1024,64]
    const float* codes = (const float*)d_in[1];  // [50000,64]

    float* c2 = (float*)d_ws;
    float* x2 = c2 + 50048;
    unsigned short* cbf = (unsigned short*)(x2 + NTOK);
    unsigned short* xbf = cbf + (size_t)NCODES * DIM;
    float* blockmin = (float*)(xbf + (size_t)NTOK * DIM);
    unsigned long long* packed = (unsigned long long*)(blockmin + (size_t)NTOK * NBLK);
    int* out = (int*)d_out;

    nn_prep_kernel<<<814, 256, 0, stream>>>(x, codes, cbf, xbf, c2, x2, packed);
    nn_stageA_kernel<<<dim3(8, NBLK), 256, 0, stream>>>(xbf, cbf, c2, blockmin);
    nn_rescan_kernel<<<(NTOK * NGRP) / 4, 256, 0, stream>>>(x, codes, c2, x2, blockmin, packed);
    nn_emit_kernel<<<(NTOK + 255) / 256, 256, 0, stream>>>(packed, out);
}

// Round 6
// 122.932 us; speedup vs baseline: 2.0721x; 1.5661x over previous
//
#include <hip/hip_runtime.h>

// Problem constants
#define NTOK   2048
#define DIM    64
#define NCODES 50000
#define THRESH 100.0f
#define BIG    3.0e38f
#define MARGIN 4.0f      // rigorous 2E bound ~2.5 (2*sum|x_i c_i|*2^-7 tail); 1.6x safety
#define NBLK   391       // 128-code MFMA blocks
#define BM32   1564      // 32-code screening blocks (391*4)
#define BM32P  1568      // padded row stride (pad entries = BIG)

typedef __attribute__((ext_vector_type(8)))  __bf16 bf16x8;
typedef __attribute__((ext_vector_type(16))) float  float16;

__device__ __forceinline__ unsigned short f2bf(float f) {
    union { float f; unsigned int u; } v; v.f = f;
    unsigned int r = v.u + 0x7FFF + ((v.u >> 16) & 1);
    return (unsigned short)(r >> 16);
}
__device__ __forceinline__ unsigned int pack2(float a, float b) {
    return (unsigned int)f2bf(a) | ((unsigned int)f2bf(b) << 16);
}

// ---------------------------------------------------------------------------
// Kernel 1 (prep): fp32 -> bf16 of codes and x, norms, bm32 pad init.
// 4 lanes per row (64 B per lane), 2-step shfl for the norm.
// ---------------------------------------------------------------------------
__global__ __launch_bounds__(256)
void nn_prep_kernel(const float* __restrict__ x, const float* __restrict__ codes,
                    unsigned short* __restrict__ cbf, unsigned short* __restrict__ xbf,
                    float* __restrict__ c2, float* __restrict__ x2,
                    float* __restrict__ bm32) {
    int g = blockIdx.x * 256 + threadIdx.x;
    if (g < NTOK * 4) {  // pad slots 1564..1567 of each token row
        int t = g >> 2;
        bm32[(size_t)t * BM32P + BM32 + (g & 3)] = BIG;
    }
    int row = g >> 2;
    int seg = g & 3;
    const float* src;
    unsigned short* dst;
    float* nrm;
    if (row < NCODES) {
        src = codes + (size_t)row * DIM + seg * 16;
        dst = cbf + (size_t)row * DIM + seg * 16;
        nrm = (seg == 0) ? (c2 + row) : nullptr;
    } else if (row < NCODES + NTOK) {
        int r = row - NCODES;
        src = x + (size_t)r * DIM + seg * 16;
        dst = xbf + (size_t)r * DIM + seg * 16;
        nrm = (seg == 0) ? (x2 + r) : nullptr;
    } else {
        return;
    }
    float4 v0 = ((const float4*)src)[0];
    float4 v1 = ((const float4*)src)[1];
    float4 v2 = ((const float4*)src)[2];
    float4 v3 = ((const float4*)src)[3];
    float s = 0.f;
    s = fmaf(v0.x, v0.x, s); s = fmaf(v0.y, v0.y, s);
    s = fmaf(v0.z, v0.z, s); s = fmaf(v0.w, v0.w, s);
    s = fmaf(v1.x, v1.x, s); s = fmaf(v1.y, v1.y, s);
    s = fmaf(v1.z, v1.z, s); s = fmaf(v1.w, v1.w, s);
    s = fmaf(v2.x, v2.x, s); s = fmaf(v2.y, v2.y, s);
    s = fmaf(v2.z, v2.z, s); s = fmaf(v2.w, v2.w, s);
    s = fmaf(v3.x, v3.x, s); s = fmaf(v3.y, v3.y, s);
    s = fmaf(v3.z, v3.z, s); s = fmaf(v3.w, v3.w, s);
    uint4 lo, hi;
    lo.x = pack2(v0.x, v0.y); lo.y = pack2(v0.z, v0.w);
    lo.z = pack2(v1.x, v1.y); lo.w = pack2(v1.z, v1.w);
    hi.x = pack2(v2.x, v2.y); hi.y = pack2(v2.z, v2.w);
    hi.z = pack2(v3.x, v3.y); hi.w = pack2(v3.z, v3.w);
    *(uint4*)dst = lo;
    *(uint4*)(dst + 8) = hi;
    s += __shfl_xor(s, 1);
    s += __shfl_xor(s, 2);
    if (nrm) *nrm = s;
}

// ---------------------------------------------------------------------------
// Kernel 2 (stage A): bf16 MFMA screening, 32-code output granularity.
// Grid: (8 token-supertiles of 256) x (391 code blocks of 128). WG = 4 waves.
// Wave w: tokens w*64..+63 x 128 codes (4 m-tiles of 32 codes x 2 n-tiles).
// acc init -c2/2 so per-token per-32-code min(d2) = -2*max(D over group mi).
// ---------------------------------------------------------------------------
__global__ __launch_bounds__(256, 2)
void nn_stageA_kernel(const unsigned short* __restrict__ xbf,
                      const unsigned short* __restrict__ cbf,
                      const float* __restrict__ c2g,
                      float* __restrict__ bm32) {
    __shared__ __bf16 xs[256 * 72];   // token tile, 144 B row stride
    __shared__ __bf16 cs[128 * 72];   // code tile
    __shared__ float  c2s[128];

    const int tid  = threadIdx.x;
    const int w    = tid >> 6;
    const int lane = tid & 63;
    const int l31  = lane & 31;
    const int h    = lane >> 5;
    const int t0   = blockIdx.x * 256;
    const int n0   = blockIdx.y * 128;

    // codes tile: 128 rows x 128 B, 8 lanes/row, 16 B/lane — coalesced
#pragma unroll
    for (int it = 0; it < 4; ++it) {
        int g = it * 256 + tid;
        int row = g >> 3, seg = g & 7;
        int n = n0 + row;
        uint4 v = make_uint4(0, 0, 0, 0);
        if (n < NCODES) v = *(const uint4*)(cbf + (size_t)n * DIM + seg * 8);
        *(uint4*)&cs[row * 72 + seg * 8] = v;
    }
    // x tile: 256 rows x 128 B
#pragma unroll
    for (int it = 0; it < 8; ++it) {
        int g = it * 256 + tid;
        int row = g >> 3, seg = g & 7;
        uint4 v = *(const uint4*)(xbf + (size_t)(t0 + row) * DIM + seg * 8);
        *(uint4*)&xs[row * 72 + seg * 8] = v;
    }
    if (tid < 128) {
        int n = n0 + tid;
        c2s[tid] = (n < NCODES) ? c2g[n] : BIG;
    }
    __syncthreads();

    // acc[mi][nj][r] = -c2[code_row]/2
    // C/D: col = lane&31 (token), row = (r&3) + 8*(r>>2) + 4*h (code)
    float16 acc[4][2];
#pragma unroll
    for (int mi = 0; mi < 4; ++mi) {
#pragma unroll
        for (int g2 = 0; g2 < 4; ++g2) {
            float4 c4 = *(float4*)&c2s[mi * 32 + g2 * 8 + 4 * h];
#pragma unroll
            for (int i = 0; i < 4; ++i) {
                float iv = -0.5f * ((float*)&c4)[i];
                acc[mi][0][g2 * 4 + i] = iv;
                acc[mi][1][g2 * 4 + i] = iv;
            }
        }
    }

    // MFMA main: K = 64 in 4 steps of 16
#pragma unroll
    for (int s = 0; s < 4; ++s) {
        bf16x8 a[4], b[2];
#pragma unroll
        for (int mi = 0; mi < 4; ++mi)
            a[mi] = *(bf16x8*)&cs[(mi * 32 + l31) * 72 + s * 16 + h * 8];
#pragma unroll
        for (int nj = 0; nj < 2; ++nj)
            b[nj] = *(bf16x8*)&xs[(w * 64 + nj * 32 + l31) * 72 + s * 16 + h * 8];
#pragma unroll
        for (int mi = 0; mi < 4; ++mi)
#pragma unroll
            for (int nj = 0; nj < 2; ++nj)
                acc[mi][nj] = __builtin_amdgcn_mfma_f32_32x32x16_bf16(
                    a[mi], b[nj], acc[mi][nj], 0, 0, 0);
    }

    // epilogue: per-token max(D) per 32-code group mi (invalid rows carry
    // ~-1.5e38 from the BIG c2 init and never win the max; an all-invalid
    // group yields blockmin ~ +3e38 -> never a candidate)
#pragma unroll
    for (int nj = 0; nj < 2; ++nj) {
#pragma unroll
        for (int mi = 0; mi < 4; ++mi) {
            float m = acc[mi][nj][0];
#pragma unroll
            for (int r = 1; r < 16; ++r) m = fmaxf(m, acc[mi][nj][r]);
            m = fmaxf(m, __shfl_xor(m, 32));   // merge h halves (code rows +4)
            if (lane < 32) {
                int token = t0 + w * 64 + nj * 32 + lane;
                bm32[(size_t)token * BM32P + blockIdx.y * 4 + mi] = -2.0f * m;
            }
        }
    }
}

// ---------------------------------------------------------------------------
// Kernel 3 (finalize): one WG per token. Scan the token's 1568 blockmins
// (coalesced, read once), LDS-reduce gmin, enqueue candidate 32-blocks in
// LDS, waves round-robin exact-fp32 rescore (2 lanes per code, 8 KB/cand),
// combine in LDS, write out[t]. No global atomics anywhere.
// ---------------------------------------------------------------------------
__global__ __launch_bounds__(256)
void nn_finalize_kernel(const float* __restrict__ x,
                        const float* __restrict__ codes,
                        const float* __restrict__ c2,
                        const float* __restrict__ x2,
                        const float* __restrict__ bm32,
                        int* __restrict__ out) {
    __shared__ float redf[8];      // [0..3] wave gmin, [4..7] wave best-v
    __shared__ int   redi[4];
    __shared__ int   queue[BM32P];
    __shared__ int   qcount;
    __shared__ float gshare;

    const int tid  = threadIdx.x;
    const int w    = tid >> 6;
    const int lane = tid & 63;
    const int t    = blockIdx.x;
    const float* bm = bm32 + (size_t)t * BM32P;

    if (tid == 0) qcount = 0;

    float v[7];
    float g = BIG;
#pragma unroll
    for (int k = 0; k < 7; ++k) {
        int b = tid + k * 256;
        v[k] = (b < BM32P) ? bm[b] : BIG;
        g = fminf(g, v[k]);
    }
#pragma unroll
    for (int m = 1; m < 64; m <<= 1) g = fminf(g, __shfl_xor(g, m));
    if (lane == 0) redf[w] = g;
    __syncthreads();
    if (tid == 0)
        gshare = fminf(fminf(redf[0], redf[1]), fminf(redf[2], redf[3])) + MARGIN;
    __syncthreads();
    const float th = gshare;

    // enqueue candidate 32-blocks (LDS atomic; queue order irrelevant —
    // the (v,id) comparator is a total order)
#pragma unroll
    for (int k = 0; k < 7; ++k) {
        int b = tid + k * 256;
        if (b < BM32P && v[k] <= th) {
            int slot = atomicAdd(&qcount, 1);
            queue[slot] = b;
        }
    }
    __syncthreads();
    const int nq = qcount;

    // per-lane x half-row (half = lane&1 selects dims [0,32) or [32,64))
    const int half = lane & 1;
    float4 xh[8];
#pragma unroll
    for (int q = 0; q < 8; ++q)
        xh[q] = *(const float4*)(x + (size_t)t * DIM + half * 32 + q * 4);
    const float x2v = x2[t];

    float bv = BIG;
    int   bi = 0x7fffffff;
    for (int e = w; e < nq; e += 4) {
        int blk = queue[e];
        int n = blk * 32 + (lane >> 1);
        if (n < NCODES) {   // pair-uniform predicate (both lanes share n)
            const float4* cp = (const float4*)(codes + (size_t)n * DIM + half * 32);
            float d = 0.f;
#pragma unroll
            for (int q = 0; q < 8; ++q) {
                float4 c4 = cp[q];
                d = fmaf(xh[q].x, c4.x, d);
                d = fmaf(xh[q].y, c4.y, d);
                d = fmaf(xh[q].z, c4.z, d);
                d = fmaf(xh[q].w, c4.w, d);
            }
            d += __shfl_xor(d, 1);   // full 64-dim dot in both pair lanes
            float d2 = fmaxf(fmaf(-2.f, d, x2v + c2[n]), 0.f);
            if (d2 < bv || (d2 == bv && n < bi)) { bv = d2; bi = n; }
        }
    }
    // wave reduce (v, id) — first-occurrence comparator
#pragma unroll
    for (int m = 1; m < 64; m <<= 1) {
        float vv = __shfl_xor(bv, m);
        int   ii = __shfl_xor(bi, m);
        if (vv < bv || (vv == bv && ii < bi)) { bv = vv; bi = ii; }
    }
    if (lane == 0) { redf[4 + w] = bv; redi[w] = bi; }
    __syncthreads();
    if (tid == 0) {
        float fb = BIG;
        int   fi = 0x7fffffff;
#pragma unroll
        for (int i = 0; i < 4; ++i) {
            float vv = redf[4 + i];
            int   ii = redi[i];
            if (vv < fb || (vv == fb && ii < fi)) { fb = vv; fi = ii; }
        }
        out[t] = (fb <= THRESH) ? fi : -1;
    }
}

// ---------------------------------------------------------------------------
// Workspace: c2[50048]f | x2[2048]f | cbf[50000*64]u16 | xbf[2048*64]u16 |
//            bm32[2048*1568]f   (~19.7 MB)
// ---------------------------------------------------------------------------
extern "C" void kernel_launch(void* const* d_in, const int* in_sizes, int n_in,
                              void* d_out, int out_size, void* d_ws, size_t ws_size,
                              hipStream_t stream) {
    const float* x     = (const float*)d_in[0];  // [2,1024,64]
    const float* codes = (const float*)d_in[1];  // [50000,64]

    float* c2 = (float*)d_ws;
    float* x2 = c2 + 50048;
    unsigned short* cbf = (unsigned short*)(x2 + NTOK);
    unsigned short* xbf = cbf + (size_t)NCODES * DIM;
    float* bm32 = (float*)(xbf + (size_t)NTOK * DIM);
    int* out = (int*)d_out;

    nn_prep_kernel<<<814, 256, 0, stream>>>(x, codes, cbf, xbf, c2, x2, bm32);
    nn_stageA_kernel<<<dim3(8, NBLK), 256, 0, stream>>>(xbf, cbf, c2, bm32);
    nn_finalize_kernel<<<NTOK, 256, 0, stream>>>(x, codes, c2, x2, bm32, out);
}

// Round 7
// 113.233 us; speedup vs baseline: 2.2495x; 1.0857x over previous
//
#include <hip/hip_runtime.h>

// Problem constants
#define NTOK   2048
#define DIM    64
#define NCODES 50000
#define THRESH 100.0f
#define BIG    3.0e38f
#define MARGIN 4.0f      // rigorous 2E bound ~2.5; 1.6x safety
#define NBLK   391       // 128-code MFMA blocks
#define BM32   1564      // 32-code screening blocks (391*4)
#define BM32P  1568      // padded row stride (pad entries = BIG)
#define NCG    56        // code groups of 7 blocks (56*7 = 392 >= 391)

typedef __attribute__((ext_vector_type(8)))  __bf16 bf16x8;
typedef __attribute__((ext_vector_type(16))) float  float16;

__device__ __forceinline__ unsigned short f2bf(float f) {
    union { float f; unsigned int u; } v; v.f = f;
    unsigned int r = v.u + 0x7FFF + ((v.u >> 16) & 1);
    return (unsigned short)(r >> 16);
}
__device__ __forceinline__ unsigned int pack2(float a, float b) {
    return (unsigned int)f2bf(a) | ((unsigned int)f2bf(b) << 16);
}

// ---------------------------------------------------------------------------
// Kernel 1 (prep): fp32 -> bf16 of codes and x, norms, bm32 pad init.
// ---------------------------------------------------------------------------
__global__ __launch_bounds__(256)
void nn_prep_kernel(const float* __restrict__ x, const float* __restrict__ codes,
                    unsigned short* __restrict__ cbf, unsigned short* __restrict__ xbf,
                    float* __restrict__ c2, float* __restrict__ x2,
                    float* __restrict__ bm32) {
    int g = blockIdx.x * 256 + threadIdx.x;
    if (g < NTOK * 4) {  // pad slots 1564..1567 of each token row
        int t = g >> 2;
        bm32[(size_t)t * BM32P + BM32 + (g & 3)] = BIG;
    }
    int row = g >> 2;
    int seg = g & 3;
    const float* src;
    unsigned short* dst;
    float* nrm;
    if (row < NCODES) {
        src = codes + (size_t)row * DIM + seg * 16;
        dst = cbf + (size_t)row * DIM + seg * 16;
        nrm = (seg == 0) ? (c2 + row) : nullptr;
    } else if (row < NCODES + NTOK) {
        int r = row - NCODES;
        src = x + (size_t)r * DIM + seg * 16;
        dst = xbf + (size_t)r * DIM + seg * 16;
        nrm = (seg == 0) ? (x2 + r) : nullptr;
    } else {
        return;
    }
    float4 v0 = ((const float4*)src)[0];
    float4 v1 = ((const float4*)src)[1];
    float4 v2 = ((const float4*)src)[2];
    float4 v3 = ((const float4*)src)[3];
    float s = 0.f;
    s = fmaf(v0.x, v0.x, s); s = fmaf(v0.y, v0.y, s);
    s = fmaf(v0.z, v0.z, s); s = fmaf(v0.w, v0.w, s);
    s = fmaf(v1.x, v1.x, s); s = fmaf(v1.y, v1.y, s);
    s = fmaf(v1.z, v1.z, s); s = fmaf(v1.w, v1.w, s);
    s = fmaf(v2.x, v2.x, s); s = fmaf(v2.y, v2.y, s);
    s = fmaf(v2.z, v2.z, s); s = fmaf(v2.w, v2.w, s);
    s = fmaf(v3.x, v3.x, s); s = fmaf(v3.y, v3.y, s);
    s = fmaf(v3.z, v3.z, s); s = fmaf(v3.w, v3.w, s);
    uint4 lo, hi;
    lo.x = pack2(v0.x, v0.y); lo.y = pack2(v0.z, v0.w);
    lo.z = pack2(v1.x, v1.y); lo.w = pack2(v1.z, v1.w);
    hi.x = pack2(v2.x, v2.y); hi.y = pack2(v2.z, v2.w);
    hi.z = pack2(v3.x, v3.y); hi.w = pack2(v3.z, v3.w);
    *(uint4*)dst = lo;
    *(uint4*)(dst + 8) = hi;
    s += __shfl_xor(s, 1);
    s += __shfl_xor(s, 2);
    if (nrm) *nrm = s;
}

// ---------------------------------------------------------------------------
// Kernel 2 (stage A): bf16 MFMA screening, n-loop form.
// Grid: (56 code groups of 7 blocks) x (8 token supertiles of 256).
// blockIdx.x fastest in linear id -> the 8 supertile-copies of one code
// group land on the same XCD (round-robin heuristic): codes L2-resident.
// Per WG: B (token) fragments gathered from global ONCE into registers;
// loop over <=7 code blocks of 128: reg-prefetch -> LDS -> 32 MFMA/wave ->
// per-32-code-group max epilogue -> bm32. No x LDS staging at all.
// ---------------------------------------------------------------------------
__global__ __launch_bounds__(256, 2)
void nn_stageA_kernel(const unsigned short* __restrict__ xbf,
                      const unsigned short* __restrict__ cbf,
                      const float* __restrict__ c2g,
                      float* __restrict__ bm32) {
    __shared__ __bf16 cs[128 * 72];   // code tile, 144 B row stride
    __shared__ float  c2s[128];

    const int tid  = threadIdx.x;
    const int w    = tid >> 6;
    const int lane = tid & 63;
    const int l31  = lane & 31;
    const int h    = lane >> 5;
    const int g0   = blockIdx.x * 7;
    const int nb   = min(7, NBLK - g0);
    const int t0   = blockIdx.y * 256;

    // B fragments (tokens w*64..w*64+63), loop-invariant: 16 B gather/frag.
    bf16x8 bfr[4][2];
#pragma unroll
    for (int s = 0; s < 4; ++s)
#pragma unroll
        for (int nj = 0; nj < 2; ++nj)
            bfr[s][nj] = *(const bf16x8*)&xbf[
                (size_t)(t0 + w * 64 + nj * 32 + l31) * DIM + s * 16 + h * 8];

    // code-tile register prefetch
    uint4 pr[4];
    float prc;
    auto prefetch = [&](int blk) {
        int n0 = blk * 128;
#pragma unroll
        for (int it = 0; it < 4; ++it) {
            int g = it * 256 + tid;
            int row = g >> 3, seg = g & 7;
            int n = n0 + row;
            pr[it] = (n < NCODES) ? *(const uint4*)(cbf + (size_t)n * DIM + seg * 8)
                                  : make_uint4(0, 0, 0, 0);
        }
        if (tid < 128) {
            int n = n0 + tid;
            prc = (n < NCODES) ? c2g[n] : BIG;
        }
    };
    prefetch(g0);

    for (int t = 0; t < nb; ++t) {
        const int blk = g0 + t;
        __syncthreads();   // previous iter's readers done with cs/c2s

        // regs -> LDS (conflict-free: 2 lanes/bank)
#pragma unroll
        for (int it = 0; it < 4; ++it) {
            int g = it * 256 + tid;
            int row = g >> 3, seg = g & 7;
            *(uint4*)&cs[row * 72 + seg * 8] = pr[it];
        }
        if (tid < 128) c2s[tid] = prc;
        if (t + 1 < nb) prefetch(blk + 1);   // latency hides under compute
        __syncthreads();

        // acc[mi][nj][r] = -c2[code_row]/2
        // C/D: col = lane&31 (token), row = (r&3) + 8*(r>>2) + 4*h (code)
        float16 acc[4][2];
#pragma unroll
        for (int mi = 0; mi < 4; ++mi) {
#pragma unroll
            for (int g2 = 0; g2 < 4; ++g2) {
                float4 c4 = *(float4*)&c2s[mi * 32 + g2 * 8 + 4 * h];
#pragma unroll
                for (int i = 0; i < 4; ++i) {
                    float iv = -0.5f * ((float*)&c4)[i];
                    acc[mi][0][g2 * 4 + i] = iv;
                    acc[mi][1][g2 * 4 + i] = iv;
                }
            }
        }

        // K = 64 in 4 steps of 16; A from LDS, B from registers
#pragma unroll
        for (int s = 0; s < 4; ++s) {
            bf16x8 a[4];
#pragma unroll
            for (int mi = 0; mi < 4; ++mi)
                a[mi] = *(bf16x8*)&cs[(mi * 32 + l31) * 72 + s * 16 + h * 8];
#pragma unroll
            for (int mi = 0; mi < 4; ++mi)
#pragma unroll
                for (int nj = 0; nj < 2; ++nj)
                    acc[mi][nj] = __builtin_amdgcn_mfma_f32_32x32x16_bf16(
                        a[mi], bfr[s][nj], acc[mi][nj], 0, 0, 0);
        }

        // epilogue: per-token max(D) per 32-code group mi (invalid rows get
        // ~-1.5e38 from BIG c2 init -> never win; all-invalid group yields
        // +3e38 -> never a candidate)
#pragma unroll
        for (int nj = 0; nj < 2; ++nj) {
#pragma unroll
            for (int mi = 0; mi < 4; ++mi) {
                float m = acc[mi][nj][0];
#pragma unroll
                for (int r = 1; r < 16; ++r) m = fmaxf(m, acc[mi][nj][r]);
                m = fmaxf(m, __shfl_xor(m, 32));  // merge h halves (rows +4)
                if (lane < 32) {
                    int token = t0 + w * 64 + nj * 32 + lane;
                    bm32[(size_t)token * BM32P + blk * 4 + mi] = -2.0f * m;
                }
            }
        }
    }
}

// ---------------------------------------------------------------------------
// Kernel 3 (finalize): one WG per token. Scan 1568 blockmins once, LDS-reduce
// gmin, LDS-enqueue candidate 32-blocks, waves round-robin exact-fp32
// rescore (2 lanes/code, 8 KB/cand), write out[t]. No global atomics.
// ---------------------------------------------------------------------------
__global__ __launch_bounds__(256)
void nn_finalize_kernel(const float* __restrict__ x,
                        const float* __restrict__ codes,
                        const float* __restrict__ c2,
                        const float* __restrict__ x2,
                        const float* __restrict__ bm32,
                        int* __restrict__ out) {
    __shared__ float redf[8];      // [0..3] wave gmin, [4..7] wave best-v
    __shared__ int   redi[4];
    __shared__ int   queue[BM32P];
    __shared__ int   qcount;
    __shared__ float gshare;

    const int tid  = threadIdx.x;
    const int w    = tid >> 6;
    const int lane = tid & 63;
    const int t    = blockIdx.x;
    const float* bm = bm32 + (size_t)t * BM32P;

    if (tid == 0) qcount = 0;

    float v[7];
    float g = BIG;
#pragma unroll
    for (int k = 0; k < 7; ++k) {
        int b = tid + k * 256;
        v[k] = (b < BM32P) ? bm[b] : BIG;
        g = fminf(g, v[k]);
    }
#pragma unroll
    for (int m = 1; m < 64; m <<= 1) g = fminf(g, __shfl_xor(g, m));
    if (lane == 0) redf[w] = g;
    __syncthreads();
    if (tid == 0)
        gshare = fminf(fminf(redf[0], redf[1]), fminf(redf[2], redf[3])) + MARGIN;
    __syncthreads();
    const float th = gshare;

    // enqueue candidates (LDS atomic; order irrelevant — (v,id) total order)
#pragma unroll
    for (int k = 0; k < 7; ++k) {
        int b = tid + k * 256;
        if (b < BM32P && v[k] <= th) {
            int slot = atomicAdd(&qcount, 1);
            queue[slot] = b;
        }
    }
    __syncthreads();
    const int nq = qcount;

    // per-lane x half-row (half = lane&1 -> dims [0,32) or [32,64))
    const int half = lane & 1;
    float4 xh[8];
#pragma unroll
    for (int q = 0; q < 8; ++q)
        xh[q] = *(const float4*)(x + (size_t)t * DIM + half * 32 + q * 4);
    const float x2v = x2[t];

    float bv = BIG;
    int   bi = 0x7fffffff;
    for (int e = w; e < nq; e += 4) {
        int blk = queue[e];
        int n = blk * 32 + (lane >> 1);
        if (n < NCODES) {   // pair-uniform predicate
            const float4* cp = (const float4*)(codes + (size_t)n * DIM + half * 32);
            float d = 0.f;
#pragma unroll
            for (int q = 0; q < 8; ++q) {
                float4 c4 = cp[q];
                d = fmaf(xh[q].x, c4.x, d);
                d = fmaf(xh[q].y, c4.y, d);
                d = fmaf(xh[q].z, c4.z, d);
                d = fmaf(xh[q].w, c4.w, d);
            }
            d += __shfl_xor(d, 1);   // full 64-dim dot in both pair lanes
            float d2 = fmaxf(fmaf(-2.f, d, x2v + c2[n]), 0.f);
            if (d2 < bv || (d2 == bv && n < bi)) { bv = d2; bi = n; }
        }
    }
#pragma unroll
    for (int m = 1; m < 64; m <<= 1) {
        float vv = __shfl_xor(bv, m);
        int   ii = __shfl_xor(bi, m);
        if (vv < bv || (vv == bv && ii < bi)) { bv = vv; bi = ii; }
    }
    if (lane == 0) { redf[4 + w] = bv; redi[w] = bi; }
    __syncthreads();
    if (tid == 0) {
        float fb = BIG;
        int   fi = 0x7fffffff;
#pragma unroll
        for (int i = 0; i < 4; ++i) {
            float vv = redf[4 + i];
            int   ii = redi[i];
            if (vv < fb || (vv == fb && ii < fi)) { fb = vv; fi = ii; }
        }
        out[t] = (fb <= THRESH) ? fi : -1;
    }
}

// ---------------------------------------------------------------------------
// Workspace: c2[50048]f | x2[2048]f | cbf[50000*64]u16 | xbf[2048*64]u16 |
//            bm32[2048*1568]f   (~19.7 MB)
// ---------------------------------------------------------------------------
extern "C" void kernel_launch(void* const* d_in, const int* in_sizes, int n_in,
                              void* d_out, int out_size, void* d_ws, size_t ws_size,
                              hipStream_t stream) {
    const float* x     = (const float*)d_in[0];  // [2,1024,64]
    const float* codes = (const float*)d_in[1];  // [50000,64]

    float* c2 = (float*)d_ws;
    float* x2 = c2 + 50048;
    unsigned short* cbf = (unsigned short*)(x2 + NTOK);
    unsigned short* xbf = cbf + (size_t)NCODES * DIM;
    float* bm32 = (float*)(xbf + (size_t)NTOK * DIM);
    int* out = (int*)d_out;

    nn_prep_kernel<<<814, 256, 0, stream>>>(x, codes, cbf, xbf, c2, x2, bm32);
    nn_stageA_kernel<<<dim3(NCG, 8), 256, 0, stream>>>(xbf, cbf, c2, bm32);
    nn_finalize_kernel<<<NTOK, 256, 0, stream>>>(x, codes, c2, x2, bm32, out);
}

// Round 8
// 112.838 us; speedup vs baseline: 2.2574x; 1.0035x over previous
//
#include <hip/hip_runtime.h>

// Problem constants
#define NTOK   2048
#define DIM    64
#define NCODES 50000
#define THRESH 100.0f
#define BIG    3.0e38f
#define MARGIN 4.0f      // rigorous 2E bound ~2.5; 1.6x safety
#define NBLK   391       // 128-code MFMA blocks
#define BM32   1564      // 32-code screening blocks (391*4)
#define BM32P  1568      // padded row stride (pad entries = BIG)
#define NCG    64        // code groups: first 7 have 7 blocks, rest 6 (7*7+57*6=391)

typedef __attribute__((ext_vector_type(8)))  __bf16 bf16x8;
typedef __attribute__((ext_vector_type(16))) float  float16;

__device__ __forceinline__ unsigned short f2bf(float f) {
    union { float f; unsigned int u; } v; v.f = f;
    unsigned int r = v.u + 0x7FFF + ((v.u >> 16) & 1);
    return (unsigned short)(r >> 16);
}
__device__ __forceinline__ unsigned int pack2(float a, float b) {
    return (unsigned int)f2bf(a) | ((unsigned int)f2bf(b) << 16);
}

// ---------------------------------------------------------------------------
// Kernel 1 (prep): x only — fp32 -> bf16 (xbf), x2 norms, bm32 pad init.
// 2048 rows x 4 lanes = 8192 threads = 32 WGs.
// ---------------------------------------------------------------------------
__global__ __launch_bounds__(256)
void nn_prep_kernel(const float* __restrict__ x,
                    unsigned short* __restrict__ xbf,
                    float* __restrict__ x2,
                    float* __restrict__ bm32) {
    int g = blockIdx.x * 256 + threadIdx.x;   // 0..8191
    {   // pad slots 1564..1567 of each token row
        int t = g >> 2;
        bm32[(size_t)t * BM32P + BM32 + (g & 3)] = BIG;
    }
    int row = g >> 2;
    int seg = g & 3;
    const float* src = x + (size_t)row * DIM + seg * 16;
    unsigned short* dst = xbf + (size_t)row * DIM + seg * 16;
    float4 v0 = ((const float4*)src)[0];
    float4 v1 = ((const float4*)src)[1];
    float4 v2 = ((const float4*)src)[2];
    float4 v3 = ((const float4*)src)[3];
    float s = 0.f;
    s = fmaf(v0.x, v0.x, s); s = fmaf(v0.y, v0.y, s);
    s = fmaf(v0.z, v0.z, s); s = fmaf(v0.w, v0.w, s);
    s = fmaf(v1.x, v1.x, s); s = fmaf(v1.y, v1.y, s);
    s = fmaf(v1.z, v1.z, s); s = fmaf(v1.w, v1.w, s);
    s = fmaf(v2.x, v2.x, s); s = fmaf(v2.y, v2.y, s);
    s = fmaf(v2.z, v2.z, s); s = fmaf(v2.w, v2.w, s);
    s = fmaf(v3.x, v3.x, s); s = fmaf(v3.y, v3.y, s);
    s = fmaf(v3.z, v3.z, s); s = fmaf(v3.w, v3.w, s);
    uint4 lo, hi;
    lo.x = pack2(v0.x, v0.y); lo.y = pack2(v0.z, v0.w);
    lo.z = pack2(v1.x, v1.y); lo.w = pack2(v1.z, v1.w);
    hi.x = pack2(v2.x, v2.y); hi.y = pack2(v2.z, v2.w);
    hi.z = pack2(v3.x, v3.y); hi.w = pack2(v3.z, v3.w);
    *(uint4*)dst = lo;
    *(uint4*)(dst + 8) = hi;
    s += __shfl_xor(s, 1);
    s += __shfl_xor(s, 2);
    if (seg == 0) x2[row] = s;
}

// ---------------------------------------------------------------------------
// Kernel 2 (stage A): bf16 MFMA screening, n-loop, fp32 codes read directly.
// Grid: (64 code groups of 6-7 blocks) x (8 token supertiles of 256) = 512
// WGs = exactly 2/CU. Linear id mod 8 = blockIdx.x mod 8 -> all 8 supertile
// copies of one code group share an XCD: per-XCD code working set ~1.8 MB,
// L2-resident after first touch.
// Per WG: B (token) fragments in registers (loop-invariant); per block-iter
// reg-prefetch fp32 codes (+inline bf16 pack and c2 partial) -> LDS ->
// 32 MFMA/wave -> per-32-code max epilogue -> bm32.
// ---------------------------------------------------------------------------
__global__ __launch_bounds__(256, 2)
void nn_stageA_kernel(const unsigned short* __restrict__ xbf,
                      const float* __restrict__ codes,
                      float* __restrict__ bm32) {
    __shared__ __bf16 cs[128 * 72];   // code tile, 144 B row stride
    __shared__ float  c2s[128];

    const int tid  = threadIdx.x;
    const int w    = tid >> 6;
    const int lane = tid & 63;
    const int l31  = lane & 31;
    const int h    = lane >> 5;
    const int gi   = blockIdx.x;
    const int g0   = 6 * gi + min(gi, 7);
    const int nb   = (gi < 7) ? 7 : 6;
    const int t0   = blockIdx.y * 256;

    // B fragments (tokens w*64..w*64+63), loop-invariant
    bf16x8 bfr[4][2];
#pragma unroll
    for (int s = 0; s < 4; ++s)
#pragma unroll
        for (int nj = 0; nj < 2; ++nj)
            bfr[s][nj] = *(const bf16x8*)&xbf[
                (size_t)(t0 + w * 64 + nj * 32 + l31) * DIM + s * 16 + h * 8];

    // code-tile register prefetch: 128 rows x 64 fp32; 4 lanes/row
    // (seg = 16 floats = 64 B per lane), 2 slots per thread.
    uint4 pr[2][2];
    float prc[2];
    auto prefetch = [&](int blk) {
        int n0 = blk * 128;
#pragma unroll
        for (int it = 0; it < 2; ++it) {
            int slot = it * 256 + tid;
            int row = slot >> 2, seg = slot & 3;
            int n = n0 + row;
            float4 f0, f1, f2, f3;
            if (n < NCODES) {
                const float4* p = (const float4*)(codes + (size_t)n * DIM + seg * 16);
                f0 = p[0]; f1 = p[1]; f2 = p[2]; f3 = p[3];
            } else {
                f0 = f1 = f2 = f3 = make_float4(0.f, 0.f, 0.f, 0.f);
            }
            float s = 0.f;
            s = fmaf(f0.x, f0.x, s); s = fmaf(f0.y, f0.y, s);
            s = fmaf(f0.z, f0.z, s); s = fmaf(f0.w, f0.w, s);
            s = fmaf(f1.x, f1.x, s); s = fmaf(f1.y, f1.y, s);
            s = fmaf(f1.z, f1.z, s); s = fmaf(f1.w, f1.w, s);
            s = fmaf(f2.x, f2.x, s); s = fmaf(f2.y, f2.y, s);
            s = fmaf(f2.z, f2.z, s); s = fmaf(f2.w, f2.w, s);
            s = fmaf(f3.x, f3.x, s); s = fmaf(f3.y, f3.y, s);
            s = fmaf(f3.z, f3.z, s); s = fmaf(f3.w, f3.w, s);
            pr[it][0].x = pack2(f0.x, f0.y); pr[it][0].y = pack2(f0.z, f0.w);
            pr[it][0].z = pack2(f1.x, f1.y); pr[it][0].w = pack2(f1.z, f1.w);
            pr[it][1].x = pack2(f2.x, f2.y); pr[it][1].y = pack2(f2.z, f2.w);
            pr[it][1].z = pack2(f3.x, f3.y); pr[it][1].w = pack2(f3.z, f3.w);
            // screening-only c2 (any association; MARGIN absorbs ulps)
            s += __shfl_xor(s, 1);
            s += __shfl_xor(s, 2);
            prc[it] = (n < NCODES) ? s : BIG;
        }
    };
    prefetch(g0);

    for (int t = 0; t < nb; ++t) {
        const int blk = g0 + t;
        __syncthreads();   // previous iter's readers done with cs/c2s

        // regs -> LDS (b128 quad-starts cover 8 lanes/quad -> conflict-free)
#pragma unroll
        for (int it = 0; it < 2; ++it) {
            int slot = it * 256 + tid;
            int row = slot >> 2, seg = slot & 3;
            *(uint4*)&cs[row * 72 + seg * 16] = pr[it][0];
            *(uint4*)&cs[row * 72 + seg * 16 + 8] = pr[it][1];
            if (seg == 0) c2s[row] = prc[it];
        }
        if (t + 1 < nb) prefetch(blk + 1);   // latency hides under compute
        __syncthreads();

        // acc[mi][nj][r] = -c2[code_row]/2
        // C/D: col = lane&31 (token), row = (r&3) + 8*(r>>2) + 4*h (code)
        float16 acc[4][2];
#pragma unroll
        for (int mi = 0; mi < 4; ++mi) {
#pragma unroll
            for (int g2 = 0; g2 < 4; ++g2) {
                float4 c4 = *(float4*)&c2s[mi * 32 + g2 * 8 + 4 * h];
#pragma unroll
                for (int i = 0; i < 4; ++i) {
                    float iv = -0.5f * ((float*)&c4)[i];
                    acc[mi][0][g2 * 4 + i] = iv;
                    acc[mi][1][g2 * 4 + i] = iv;
                }
            }
        }

        // K = 64 in 4 steps of 16; A from LDS, B from registers
#pragma unroll
        for (int s = 0; s < 4; ++s) {
            bf16x8 a[4];
#pragma unroll
            for (int mi = 0; mi < 4; ++mi)
                a[mi] = *(bf16x8*)&cs[(mi * 32 + l31) * 72 + s * 16 + h * 8];
#pragma unroll
            for (int mi = 0; mi < 4; ++mi)
#pragma unroll
                for (int nj = 0; nj < 2; ++nj)
                    acc[mi][nj] = __builtin_amdgcn_mfma_f32_32x32x16_bf16(
                        a[mi], bfr[s][nj], acc[mi][nj], 0, 0, 0);
        }

        // epilogue: per-token max(D) per 32-code group mi (invalid rows get
        // ~-1.5e38 from BIG c2 init -> never win; all-invalid group yields
        // +3e38 -> never a candidate)
#pragma unroll
        for (int nj = 0; nj < 2; ++nj) {
#pragma unroll
            for (int mi = 0; mi < 4; ++mi) {
                float m = acc[mi][nj][0];
#pragma unroll
                for (int r = 1; r < 16; ++r) m = fmaxf(m, acc[mi][nj][r]);
                m = fmaxf(m, __shfl_xor(m, 32));  // merge h halves (rows +4)
                if (lane < 32) {
                    int token = t0 + w * 64 + nj * 32 + lane;
                    bm32[(size_t)token * BM32P + blk * 4 + mi] = -2.0f * m;
                }
            }
        }
    }
}

// ---------------------------------------------------------------------------
// Kernel 3 (finalize): one WG per token. Scan 1568 blockmins once, LDS-reduce
// gmin, LDS-enqueue candidate 32-blocks, waves round-robin exact-fp32
// rescore (2 lanes/code, 8 KB/cand). c2 recomputed inline with prep's EXACT
// fmaf association -> bit-identical to the deleted c2 array. No global
// atomics anywhere.
// ---------------------------------------------------------------------------
__global__ __launch_bounds__(256)
void nn_finalize_kernel(const float* __restrict__ x,
                        const float* __restrict__ codes,
                        const float* __restrict__ x2,
                        const float* __restrict__ bm32,
                        int* __restrict__ out) {
    __shared__ float redf[8];      // [0..3] wave gmin, [4..7] wave best-v
    __shared__ int   redi[4];
    __shared__ int   queue[BM32P];
    __shared__ int   qcount;
    __shared__ float gshare;

    const int tid  = threadIdx.x;
    const int w    = tid >> 6;
    const int lane = tid & 63;
    const int t    = blockIdx.x;
    const float* bm = bm32 + (size_t)t * BM32P;

    if (tid == 0) qcount = 0;

    float v[7];
    float g = BIG;
#pragma unroll
    for (int k = 0; k < 7; ++k) {
        int b = tid + k * 256;
        v[k] = (b < BM32P) ? bm[b] : BIG;
        g = fminf(g, v[k]);
    }
#pragma unroll
    for (int m = 1; m < 64; m <<= 1) g = fminf(g, __shfl_xor(g, m));
    if (lane == 0) redf[w] = g;
    __syncthreads();
    if (tid == 0)
        gshare = fminf(fminf(redf[0], redf[1]), fminf(redf[2], redf[3])) + MARGIN;
    __syncthreads();
    const float th = gshare;

    // enqueue candidates (LDS atomic; order irrelevant — (v,id) total order)
#pragma unroll
    for (int k = 0; k < 7; ++k) {
        int b = tid + k * 256;
        if (b < BM32P && v[k] <= th) {
            int slot = atomicAdd(&qcount, 1);
            queue[slot] = b;
        }
    }
    __syncthreads();
    const int nq = qcount;

    // per-lane x half-row (half = lane&1 -> dims [0,32) or [32,64))
    const int half = lane & 1;
    float4 xh[8];
#pragma unroll
    for (int q = 0; q < 8; ++q)
        xh[q] = *(const float4*)(x + (size_t)t * DIM + half * 32 + q * 4);
    const float x2v = x2[t];

    float bv = BIG;
    int   bi = 0x7fffffff;
    for (int e = w; e < nq; e += 4) {
        int blk = queue[e];
        int n = blk * 32 + (lane >> 1);
        if (n < NCODES) {   // pair-uniform predicate
            const float4* cp = (const float4*)(codes + (size_t)n * DIM + half * 32);
            float4 c4[8];
#pragma unroll
            for (int q = 0; q < 8; ++q) c4[q] = cp[q];
            // dot (same association as prior passing rounds)
            float d = 0.f;
#pragma unroll
            for (int q = 0; q < 8; ++q) {
                d = fmaf(xh[q].x, c4[q].x, d);
                d = fmaf(xh[q].y, c4[q].y, d);
                d = fmaf(xh[q].z, c4[q].z, d);
                d = fmaf(xh[q].w, c4[q].w, d);
            }
            d += __shfl_xor(d, 1);   // full 64-dim dot in both pair lanes
            // c2 with prep's exact association: s_seg = 16-elem fmaf chain,
            // c2 = (s0+s1)+(s2+s3)
            float sa = 0.f, sb = 0.f;
#pragma unroll
            for (int q = 0; q < 4; ++q) {
                sa = fmaf(c4[q].x, c4[q].x, sa); sa = fmaf(c4[q].y, c4[q].y, sa);
                sa = fmaf(c4[q].z, c4[q].z, sa); sa = fmaf(c4[q].w, c4[q].w, sa);
            }
#pragma unroll
            for (int q = 4; q < 8; ++q) {
                sb = fmaf(c4[q].x, c4[q].x, sb); sb = fmaf(c4[q].y, c4[q].y, sb);
                sb = fmaf(c4[q].z, c4[q].z, sb); sb = fmaf(c4[q].w, c4[q].w, sb);
            }
            float mysum = sa + sb;                  // half0: s0+s1, half1: s2+s3
            float other = __shfl_xor(mysum, 1);
            float c2v = half ? (other + mysum) : (mysum + other);
            float d2 = fmaxf(fmaf(-2.f, d, x2v + c2v), 0.f);
            if (d2 < bv || (d2 == bv && n < bi)) { bv = d2; bi = n; }
        }
    }
#pragma unroll
    for (int m = 1; m < 64; m <<= 1) {
        float vv = __shfl_xor(bv, m);
        int   ii = __shfl_xor(bi, m);
        if (vv < bv || (vv == bv && ii < bi)) { bv = vv; bi = ii; }
    }
    if (lane == 0) { redf[4 + w] = bv; redi[w] = bi; }
    __syncthreads();
    if (tid == 0) {
        float fb = BIG;
        int   fi = 0x7fffffff;
#pragma unroll
        for (int i = 0; i < 4; ++i) {
            float vv = redf[4 + i];
            int   ii = redi[i];
            if (vv < fb || (vv == fb && ii < fi)) { fb = vv; fi = ii; }
        }
        out[t] = (fb <= THRESH) ? fi : -1;
    }
}

// ---------------------------------------------------------------------------
// Workspace: x2[2048]f | xbf[2048*64]u16 | bm32[2048*1568]f   (~13.1 MB)
// ---------------------------------------------------------------------------
extern "C" void kernel_launch(void* const* d_in, const int* in_sizes, int n_in,
                              void* d_out, int out_size, void* d_ws, size_t ws_size,
                              hipStream_t stream) {
    const float* x     = (const float*)d_in[0];  // [2,1024,64]
    const float* codes = (const float*)d_in[1];  // [50000,64]

    float* x2 = (float*)d_ws;
    unsigned short* xbf = (unsigned short*)(x2 + NTOK);
    float* bm32 = (float*)(xbf + (size_t)NTOK * DIM);
    int* out = (int*)d_out;

    nn_prep_kernel<<<32, 256, 0, stream>>>(x, xbf, x2, bm32);
    nn_stageA_kernel<<<dim3(NCG, 8), 256, 0, stream>>>(xbf, codes, bm32);
    nn_finalize_kernel<<<NTOK, 256, 0, stream>>>(x, codes, x2, bm32, out);
}

// Round 9
// 107.740 us; speedup vs baseline: 2.3642x; 1.0473x over previous
//
#include <hip/hip_runtime.h>

// Problem constants
#define NTOK   2048
#define DIM    64
#define NCODES 50000
#define THRESH 100.0f
#define BIG    3.0e38f
#define MARGIN 4.0f      // rigorous 2E bound ~2.5; 1.6x safety
#define NBLK   391       // 128-code MFMA blocks
#define BM32   1564      // 32-code screening blocks (391*4)
#define BM32P  1568      // padded row stride (pad entries = BIG)
#define NCG    64        // code groups: first 7 have 7 blocks, rest 6 (7*7+57*6=391)

typedef __attribute__((ext_vector_type(8)))  __bf16 bf16x8;
typedef __attribute__((ext_vector_type(16))) float  float16;

__device__ __forceinline__ unsigned short f2bf(float f) {
    union { float f; unsigned int u; } v; v.f = f;
    unsigned int r = v.u + 0x7FFF + ((v.u >> 16) & 1);
    return (unsigned short)(r >> 16);
}
__device__ __forceinline__ unsigned int pack2(float a, float b) {
    return (unsigned int)f2bf(a) | ((unsigned int)f2bf(b) << 16);
}

// ---------------------------------------------------------------------------
// Kernel 1 (prep): fp32 -> bf16 of codes and x, norms, bm32 pad init.
// 4 lanes per row (64 B per lane), 2-step shfl for the norm.
// ---------------------------------------------------------------------------
__global__ __launch_bounds__(256)
void nn_prep_kernel(const float* __restrict__ x, const float* __restrict__ codes,
                    unsigned short* __restrict__ cbf, unsigned short* __restrict__ xbf,
                    float* __restrict__ c2, float* __restrict__ x2,
                    float* __restrict__ bm32) {
    int g = blockIdx.x * 256 + threadIdx.x;
    if (g < NTOK * 4) {  // pad slots 1564..1567 of each token row
        int t = g >> 2;
        bm32[(size_t)t * BM32P + BM32 + (g & 3)] = BIG;
    }
    int row = g >> 2;
    int seg = g & 3;
    const float* src;
    unsigned short* dst;
    float* nrm;
    if (row < NCODES) {
        src = codes + (size_t)row * DIM + seg * 16;
        dst = cbf + (size_t)row * DIM + seg * 16;
        nrm = (seg == 0) ? (c2 + row) : nullptr;
    } else if (row < NCODES + NTOK) {
        int r = row - NCODES;
        src = x + (size_t)r * DIM + seg * 16;
        dst = xbf + (size_t)r * DIM + seg * 16;
        nrm = (seg == 0) ? (x2 + r) : nullptr;
    } else {
        return;
    }
    float4 v0 = ((const float4*)src)[0];
    float4 v1 = ((const float4*)src)[1];
    float4 v2 = ((const float4*)src)[2];
    float4 v3 = ((const float4*)src)[3];
    float s = 0.f;
    s = fmaf(v0.x, v0.x, s); s = fmaf(v0.y, v0.y, s);
    s = fmaf(v0.z, v0.z, s); s = fmaf(v0.w, v0.w, s);
    s = fmaf(v1.x, v1.x, s); s = fmaf(v1.y, v1.y, s);
    s = fmaf(v1.z, v1.z, s); s = fmaf(v1.w, v1.w, s);
    s = fmaf(v2.x, v2.x, s); s = fmaf(v2.y, v2.y, s);
    s = fmaf(v2.z, v2.z, s); s = fmaf(v2.w, v2.w, s);
    s = fmaf(v3.x, v3.x, s); s = fmaf(v3.y, v3.y, s);
    s = fmaf(v3.z, v3.z, s); s = fmaf(v3.w, v3.w, s);
    uint4 lo, hi;
    lo.x = pack2(v0.x, v0.y); lo.y = pack2(v0.z, v0.w);
    lo.z = pack2(v1.x, v1.y); lo.w = pack2(v1.z, v1.w);
    hi.x = pack2(v2.x, v2.y); hi.y = pack2(v2.z, v2.w);
    hi.z = pack2(v3.x, v3.y); hi.w = pack2(v3.z, v3.w);
    *(uint4*)dst = lo;
    *(uint4*)(dst + 8) = hi;
    s += __shfl_xor(s, 1);
    s += __shfl_xor(s, 2);
    if (nrm) *nrm = s;
}

// ---------------------------------------------------------------------------
// Kernel 2 (stage A): bf16 MFMA screening, n-loop over code blocks.
// Grid: (64 code groups of 6-7 blocks) x (8 token supertiles of 256) = 512
// WGs = exactly 2/CU; blockIdx.x mod 8 -> XCD: the 8 supertile copies of one
// code group share an XCD (codes L2-resident after first touch).
// Per WG: B (token) fragments in registers (loop-invariant); per block-iter:
// reg-prefetch bf16 code tile -> LDS -> 32 MFMA/wave -> per-32-code max
// epilogue -> ONE dwordx4 store per nj (the 4 mi-values live in one lane).
// ---------------------------------------------------------------------------
__global__ __launch_bounds__(256, 2)
void nn_stageA_kernel(const unsigned short* __restrict__ xbf,
                      const unsigned short* __restrict__ cbf,
                      const float* __restrict__ c2g,
                      float* __restrict__ bm32) {
    __shared__ __bf16 cs[128 * 72];   // code tile, 144 B row stride
    __shared__ float  c2s[128];

    const int tid  = threadIdx.x;
    const int w    = tid >> 6;
    const int lane = tid & 63;
    const int l31  = lane & 31;
    const int h    = lane >> 5;
    const int gi   = blockIdx.x;
    const int g0   = 6 * gi + min(gi, 7);
    const int nb   = (gi < 7) ? 7 : 6;
    const int t0   = blockIdx.y * 256;

    // B fragments (tokens w*64..w*64+63), loop-invariant
    bf16x8 bfr[4][2];
#pragma unroll
    for (int s = 0; s < 4; ++s)
#pragma unroll
        for (int nj = 0; nj < 2; ++nj)
            bfr[s][nj] = *(const bf16x8*)&xbf[
                (size_t)(t0 + w * 64 + nj * 32 + l31) * DIM + s * 16 + h * 8];

    // code-tile register prefetch: 128 rows x 128 B bf16; 8 lanes/row
    uint4 pr[4];
    float prc;
    auto prefetch = [&](int blk) {
        int n0 = blk * 128;
#pragma unroll
        for (int it = 0; it < 4; ++it) {
            int g = it * 256 + tid;
            int row = g >> 3, seg = g & 7;
            int n = n0 + row;
            pr[it] = (n < NCODES) ? *(const uint4*)(cbf + (size_t)n * DIM + seg * 8)
                                  : make_uint4(0, 0, 0, 0);
        }
        if (tid < 128) {
            int n = n0 + tid;
            prc = (n < NCODES) ? c2g[n] : BIG;
        }
    };
    prefetch(g0);

    for (int t = 0; t < nb; ++t) {
        const int blk = g0 + t;
        __syncthreads();   // previous iter's readers done with cs/c2s

        // regs -> LDS (conflict-free)
#pragma unroll
        for (int it = 0; it < 4; ++it) {
            int g = it * 256 + tid;
            int row = g >> 3, seg = g & 7;
            *(uint4*)&cs[row * 72 + seg * 8] = pr[it];
        }
        if (tid < 128) c2s[tid] = prc;
        if (t + 1 < nb) prefetch(blk + 1);   // latency hides under compute
        __syncthreads();

        // acc[mi][nj][r] = -c2[code_row]/2   (c2s reads are 2-addr broadcasts)
        // C/D: col = lane&31 (token), row = (r&3) + 8*(r>>2) + 4*h (code)
        float16 acc[4][2];
#pragma unroll
        for (int mi = 0; mi < 4; ++mi) {
#pragma unroll
            for (int g2 = 0; g2 < 4; ++g2) {
                float4 c4 = *(float4*)&c2s[mi * 32 + g2 * 8 + 4 * h];
#pragma unroll
                for (int i = 0; i < 4; ++i) {
                    float iv = -0.5f * ((float*)&c4)[i];
                    acc[mi][0][g2 * 4 + i] = iv;
                    acc[mi][1][g2 * 4 + i] = iv;
                }
            }
        }

        // K = 64 in 4 steps of 16; A from LDS, B from registers
#pragma unroll
        for (int s = 0; s < 4; ++s) {
            bf16x8 a[4];
#pragma unroll
            for (int mi = 0; mi < 4; ++mi)
                a[mi] = *(bf16x8*)&cs[(mi * 32 + l31) * 72 + s * 16 + h * 8];
#pragma unroll
            for (int mi = 0; mi < 4; ++mi)
#pragma unroll
                for (int nj = 0; nj < 2; ++nj)
                    acc[mi][nj] = __builtin_amdgcn_mfma_f32_32x32x16_bf16(
                        a[mi], bfr[s][nj], acc[mi][nj], 0, 0, 0);
        }

        // epilogue: per-token max(D) per 32-code group mi; the 4 mi-values
        // for a token are in ONE lane -> single dwordx4 store per nj.
        // (invalid rows carry ~-1.5e38 from BIG c2 init -> never win; an
        // all-invalid group yields +3e38 -> never a candidate)
#pragma unroll
        for (int nj = 0; nj < 2; ++nj) {
            float4 o;
#pragma unroll
            for (int mi = 0; mi < 4; ++mi) {
                float m = acc[mi][nj][0];
#pragma unroll
                for (int r = 1; r < 16; ++r) m = fmaxf(m, acc[mi][nj][r]);
                m = fmaxf(m, __shfl_xor(m, 32));  // merge h halves (rows +4)
                ((float*)&o)[mi] = -2.0f * m;
            }
            if (lane < 32) {
                int token = t0 + w * 64 + nj * 32 + lane;
                *(float4*)&bm32[(size_t)token * BM32P + blk * 4] = o;
            }
        }
    }
}

// ---------------------------------------------------------------------------
// Kernel 3 (finalize): one WG per token. Scan 1568 blockmins once (coalesced
// row), LDS-reduce gmin, LDS-enqueue candidate 32-blocks, waves round-robin
// exact-fp32 rescore (2 lanes/code, 8 KB/cand) using the prep c2 array
// (same values as R6's passing run), write out[t]. No global atomics.
// ---------------------------------------------------------------------------
__global__ __launch_bounds__(256)
void nn_finalize_kernel(const float* __restrict__ x,
                        const float* __restrict__ codes,
                        const float* __restrict__ c2,
                        const float* __restrict__ x2,
                        const float* __restrict__ bm32,
                        int* __restrict__ out) {
    __shared__ float redf[8];      // [0..3] wave gmin, [4..7] wave best-v
    __shared__ int   redi[4];
    __shared__ int   queue[BM32P];
    __shared__ int   qcount;
    __shared__ float gshare;

    const int tid  = threadIdx.x;
    const int w    = tid >> 6;
    const int lane = tid & 63;
    const int t    = blockIdx.x;
    const float* bm = bm32 + (size_t)t * BM32P;

    if (tid == 0) qcount = 0;

    float v[7];
    float g = BIG;
#pragma unroll
    for (int k = 0; k < 7; ++k) {
        int b = tid + k * 256;
        v[k] = (b < BM32P) ? bm[b] : BIG;
        g = fminf(g, v[k]);
    }
#pragma unroll
    for (int m = 1; m < 64; m <<= 1) g = fminf(g, __shfl_xor(g, m));
    if (lane == 0) redf[w] = g;
    __syncthreads();
    if (tid == 0)
        gshare = fminf(fminf(redf[0], redf[1]), fminf(redf[2], redf[3])) + MARGIN;
    __syncthreads();
    const float th = gshare;

    // enqueue candidates (LDS atomic; order irrelevant — (v,id) total order)
#pragma unroll
    for (int k = 0; k < 7; ++k) {
        int b = tid + k * 256;
        if (b < BM32P && v[k] <= th) {
            int slot = atomicAdd(&qcount, 1);
            queue[slot] = b;
        }
    }
    __syncthreads();
    const int nq = qcount;

    // per-lane x half-row (half = lane&1 -> dims [0,32) or [32,64))
    const int half = lane & 1;
    float4 xh[8];
#pragma unroll
    for (int q = 0; q < 8; ++q)
        xh[q] = *(const float4*)(x + (size_t)t * DIM + half * 32 + q * 4);
    const float x2v = x2[t];

    float bv = BIG;
    int   bi = 0x7fffffff;
    for (int e = w; e < nq; e += 4) {
        int blk = queue[e];
        int n = blk * 32 + (lane >> 1);
        if (n < NCODES) {   // pair-uniform predicate
            const float4* cp = (const float4*)(codes + (size_t)n * DIM + half * 32);
            float d = 0.f;
#pragma unroll
            for (int q = 0; q < 8; ++q) {
                float4 c4 = cp[q];
                d = fmaf(xh[q].x, c4.x, d);
                d = fmaf(xh[q].y, c4.y, d);
                d = fmaf(xh[q].z, c4.z, d);
                d = fmaf(xh[q].w, c4.w, d);
            }
            d += __shfl_xor(d, 1);   // full 64-dim dot in both pair lanes
            float d2 = fmaxf(fmaf(-2.f, d, x2v + c2[n]), 0.f);
            if (d2 < bv || (d2 == bv && n < bi)) { bv = d2; bi = n; }
        }
    }
#pragma unroll
    for (int m = 1; m < 64; m <<= 1) {
        float vv = __shfl_xor(bv, m);
        int   ii = __shfl_xor(bi, m);
        if (vv < bv || (vv == bv && ii < bi)) { bv = vv; bi = ii; }
    }
    if (lane == 0) { redf[4 + w] = bv; redi[w] = bi; }
    __syncthreads();
    if (tid == 0) {
        float fb = BIG;
        int   fi = 0x7fffffff;
#pragma unroll
        for (int i = 0; i < 4; ++i) {
            float vv = redf[4 + i];
            int   ii = redi[i];
            if (vv < fb || (vv == fb && ii < fi)) { fb = vv; fi = ii; }
        }
        out[t] = (fb <= THRESH) ? fi : -1;
    }
}

// ---------------------------------------------------------------------------
// Workspace: c2[50048]f | x2[2048]f | cbf[50000*64]u16 | xbf[2048*64]u16 |
//            bm32[2048*1568]f   (~19.7 MB)
// ---------------------------------------------------------------------------
extern "C" void kernel_launch(void* const* d_in, const int* in_sizes, int n_in,
                              void* d_out, int out_size, void* d_ws, size_t ws_size,
                              hipStream_t stream) {
    const float* x     = (const float*)d_in[0];  // [2,1024,64]
    const float* codes = (const float*)d_in[1];  // [50000,64]

    float* c2 = (float*)d_ws;
    float* x2 = c2 + 50048;
    unsigned short* cbf = (unsigned short*)(x2 + NTOK);
    unsigned short* xbf = cbf + (size_t)NCODES * DIM;
    float* bm32 = (float*)(xbf + (size_t)NTOK * DIM);
    int* out = (int*)d_out;

    nn_prep_kernel<<<814, 256, 0, stream>>>(x, codes, cbf, xbf, c2, x2, bm32);
    nn_stageA_kernel<<<dim3(NCG, 8), 256, 0, stream>>>(xbf, cbf, c2, bm32);
    nn_finalize_kernel<<<NTOK, 256, 0, stream>>>(x, codes, c2, x2, bm32, out);
}